// Round 2
// baseline (43.249 us; speedup 1.0000x reference)
//
#include <hip/hip_runtime.h>

#define BATCH  16
#define LEN    512
#define NSTATE 64
#define DMODEL 256
#define TB     32      // time-batch between LDS transpose-reduces
#define WAVES  2       // waves per block (small barrier groups)
#define PAD    2       // row stride 34 floats: read/write both <=2-way (free)

__global__ __launch_bounds__(WAVES * 64, 4)
void s4d_scan_kernel(const float* __restrict__ u,
                     const float* __restrict__ Lre_p, const float* __restrict__ Lim_p,
                     const float* __restrict__ Bre_p, const float* __restrict__ Bim_p,
                     const float* __restrict__ Pre_p, const float* __restrict__ Pim_p,
                     const float* __restrict__ logdt_p,
                     float* __restrict__ y)
{
    __shared__ float cb[WAVES][NSTATE][TB + PAD];   // 2*64*34*4 = 17.4 KB

    const int tid  = threadIdx.x;
    const int lane = tid & 63;
    const int widx = tid >> 6;
    const int wid  = blockIdx.x * WAVES + widx;   // 0..4095
    const int b    = wid >> 8;                    // / DMODEL
    const int d    = wid & 255;                   // % DMODEL

    // ---- per-lane (state n = lane) coefficients --------------------------
    const float dt  = expf(logdt_p[0]);
    const float Lre = Lre_p[lane];
    const float Lim = Lim_p[lane];
    const float eL  = expf(Lre);
    // w = -exp(Lambda):  a = exp(dt*w)
    const float wre = -eL * cosf(Lim);
    const float wim = -eL * sinf(Lim);
    const float mag = expf(dt * wre);
    const float are = mag * cosf(dt * wim);
    const float aim = mag * sinf(dt * wim);
    const float Bdre = dt * Bre_p[lane];
    const float Bdim = dt * Bim_p[lane];
    const float Pre  = Pre_p[lane * DMODEL + d];
    const float Pim  = Pim_p[lane * DMODEL + d];
    // G = C * Bd  (fold output projection into the input matrix)
    const float Gre = Pre * Bdre - Pim * Bdim;
    const float Gim = Pre * Bdim + Pim * Bdre;

    float zre = 0.f, zim = 0.f;   // z = C * x  (complex, per state)

    const float* up = u + (size_t)b * LEN * DMODEL + d;   // + t*DMODEL
    float*       yp = y + (size_t)b * LEN * DMODEL + d;

    const int tl = lane & 31;     // reduce column (time slot)
    const int h  = lane >> 5;     // which half of states this lane reduces

    // prefetch first macro-batch: 64 timesteps, one per lane
    float ucur = up[lane * DMODEL];

    for (int m = 0; m < LEN / 64; ++m) {
        float unext = 0.f;
        if (m + 1 < LEN / 64)
            unext = up[((m + 1) * 64 + lane) * DMODEL];   // prefetch next 64 t's

        #pragma unroll
        for (int half = 0; half < 2; ++half) {
            #pragma unroll
            for (int tau = 0; tau < TB; tau += 2) {
                // two steps, then paired adjacent LDS stores (ds_write2 mergeable)
                const float us0 = __uint_as_float(
                    __builtin_amdgcn_readlane(__float_as_uint(ucur), half * 32 + tau));
                const float r0 = fmaf(are, zre, fmaf(-aim, zim, Gre * us0));
                const float i0 = fmaf(are, zim, fmaf( aim, zre, Gim * us0));
                const float us1 = __uint_as_float(
                    __builtin_amdgcn_readlane(__float_as_uint(ucur), half * 32 + tau + 1));
                const float r1 = fmaf(are, r0, fmaf(-aim, i0, Gre * us1));
                const float i1 = fmaf(are, i0, fmaf( aim, r0, Gim * us1));
                zre = r1; zim = i1;
                cb[widx][lane][tau]     = r0;
                cb[widx][lane][tau + 1] = r1;
            }
            __syncthreads();

            // transpose-reduce: lane (h, tl) sums states 32h..32h+31 at time tl
            float s = 0.f;
            #pragma unroll
            for (int j = 0; j < 32; ++j)
                s += cb[widx][32 * h + j][tl];
            s += __shfl_xor(s, 32, 64);        // combine the two state-halves
            if (lane < 32)
                yp[(m * 64 + half * 32 + tl) * DMODEL] = s;
            __syncthreads();                    // protect cb before next writes
        }
        ucur = unext;
    }
}

extern "C" void kernel_launch(void* const* d_in, const int* in_sizes, int n_in,
                              void* d_out, int out_size, void* d_ws, size_t ws_size,
                              hipStream_t stream) {
    const float* u      = (const float*)d_in[0];
    const float* Lre    = (const float*)d_in[1];
    const float* Lim    = (const float*)d_in[2];
    const float* Bre    = (const float*)d_in[3];
    const float* Bim    = (const float*)d_in[4];
    const float* Pre    = (const float*)d_in[5];
    const float* Pim    = (const float*)d_in[6];
    const float* logdt  = (const float*)d_in[7];
    float* y = (float*)d_out;

    const int nblocks = (BATCH * DMODEL) / WAVES;   // 2048
    s4d_scan_kernel<<<nblocks, WAVES * 64, 0, stream>>>(
        u, Lre, Lim, Bre, Bim, Pre, Pim, logdt, y);
}